// Round 4
// baseline (213.448 us; speedup 1.0000x reference)
//
#include <hip/hip_runtime.h>

#define NCH    40
#define MORD   16
#define NR     17
#define NY     42
#define NBINS  257
#define FPB    64            // frames per slab == wave size
#define SLABS  8             // slabs per block (persistent)
#define SLABF  (FPB * NBINS) // 16448 floats per slab
#define NLD    65            // global_load_lds calls per slab (64 x 1KB + 1 overlap)

// ---------------- compile-time table generation (double precision) ----------------
namespace cfg {

constexpr double PI  = 3.14159265358979323846264338327950288;
constexpr double LN2 = 0.693147180559945309417232121458176568;

constexpr double cexp(double x) {
    double t = 1.0, s = 1.0;
    for (int i = 1; i < 40; ++i) { t *= x / i; s += t; }
    return s;
}

constexpr double clog(double z) {
    double lg = 0.0;
    while (z > 1.4142135623730951) { z *= 0.5; lg += LN2; }
    while (z < 0.7071067811865476) { z *= 2.0; lg -= LN2; }
    double u = (z - 1.0) / (z + 1.0), u2 = u * u, t = u, s = u;
    for (int k = 1; k < 24; ++k) { t *= u2; s += t / (2.0 * k + 1.0); }
    return lg + 2.0 * s;
}

constexpr double ccos(double x) {
    double tp = 2.0 * PI;
    double q = x / tp;
    long long k = (long long)(q + (q >= 0.0 ? 0.5 : -0.5));
    double r = x - (double)k * tp;
    double r2 = r * r, t = 1.0, s = 1.0;
    for (int i = 1; i < 20; ++i) { t *= -r2 / ((2.0 * i - 1.0) * (2.0 * i)); s += t; }
    return s;
}

constexpr double csin(double x) { return ccos(x - PI / 2.0); }

struct Tab {
    int   start[43];
    float w[257];
    float eql[NCH];
    float lift[NR];
    float ct[NR][NY];
    constexpr Tab() : start(), w(), eql(), lift(), ct() {
        const double lmax  = clog(87.0 / 7.0);
        const double U1127 = lmax / 41.0;
        for (int c = 0; c <= 41; ++c) {
            double thr = 22.4 * (cexp((double)c * U1127) - 1.0);
            int s = (int)thr + 1;
            if (s < 1) s = 1;
            if (s > 256) s = 256;
            start[c] = s;
        }
        start[42 - 1] = start[41];
        for (int c = 0; c <= 40; ++c) {
            for (int b = start[c]; b < start[c + 1]; ++b) {
                double mel = 1127.0 * clog(1.0 + (double)b * 31.25 / 700.0);
                double t   = mel / (1127.0 * U1127);
                w[b] = (float)(t - (double)c);
            }
        }
        for (int c = 0; c < NCH; ++c) {
            double cf = 700.0 * (cexp((double)(c + 1) * U1127) - 1.0);
            double f2 = cf * cf;
            double e  = f2 / (f2 + 160000.0);
            e = e * e * (f2 + 1440000.0) / (f2 + 9610000.0);
            eql[c] = (float)e;
        }
        for (int m = 0; m < NR; ++m)
            lift[m] = (float)(1.0 + 11.0 * csin(PI * (double)m / 22.0));
        lift[0] = 2.0f;
        for (int l = 0; l < NR; ++l)
            for (int j = 0; j < NY; ++j) {
                double s = (j == 0 || j == NY - 1) ? 1.0 : 2.0;
                ct[l][j] = (float)(s * ccos(PI * (double)(j * l) / 41.0) / 82.0);
            }
    }
};

constexpr Tab T{};

} // namespace cfg

// -------- persistent 1-wave block, double-buffered global->LDS, fine vmcnt --------
__global__ __launch_bounds__(FPB, 1) void plp_kernel(const float* __restrict__ x,
                                                     float* __restrict__ out,
                                                     int nframes)
{
    using cfg::T;
    __shared__ float slab[2][SLABF];            // 2 x 65792 B = 131584 B
    const int tid = threadIdx.x;                // 0..63, one wave
    const long long blk    = blockIdx.x;
    const long long blkF0  = blk * (long long)(SLABS * FPB);   // block's first frame
    const float* gblk = x + blkF0 * NBINS;
    const float* gend = x + (long long)nframes * NBINS;
    const bool safe = (blkF0 + SLABS * FPB) <= (long long)nframes;  // uniform

    // stage slab s into buffer buf (65 x 1KB coalesced DMA, no VGPR round-trip)
    auto stage = [&](int buf, int s) {
        const float* base = gblk + (long long)s * SLABF + tid * 4;
        float* lbase = &slab[buf][0];
        if (safe) {
            #pragma unroll
            for (int k = 0; k < NLD; ++k) {
                const int off = (k < 64) ? k * 256 : (SLABF - 256);
                __builtin_amdgcn_global_load_lds(
                    (const __attribute__((address_space(1))) void*)(base + off),
                    (__attribute__((address_space(3))) void*)(lbase + off),
                    16, 0, 0);
            }
        } else {
            #pragma unroll
            for (int k = 0; k < NLD; ++k) {
                const int off = (k < 64) ? k * 256 : (SLABF - 256);
                const float* src = base + off;
                if (src + 4 > gend) src = gend - 4;
                __builtin_amdgcn_global_load_lds(
                    (const __attribute__((address_space(1))) void*)src,
                    (__attribute__((address_space(3))) void*)(lbase + off),
                    16, 0, 0);
            }
        }
    };

    stage(0, 0);   // prologue

    #pragma unroll 1
    for (int s = 0; s < SLABS; ++s) {
        if (s + 1 < SLABS) {
            stage((s + 1) & 1, s + 1);
            // in-order vmcnt: outstanding<=32 => slab s's loads (issued >=97 slots
            // earlier, incl. <=8 interleaved stores) are complete; ~32KB of s+1 stays in flight
            asm volatile("s_waitcnt vmcnt(32)" ::: "memory");
        } else {
            asm volatile("s_waitcnt vmcnt(0)" ::: "memory");
        }

        const long long frame = blkF0 + (long long)s * FPB + tid;
        if (frame < nframes) {
            const float* fr = &slab[s & 1][tid * NBINS];  // bank (tid+b)%32 -> 2-way, free

            // ---- sparse mel filterbank: compile-time indices & literal weights ----
            float fb[NCH];
            #pragma unroll
            for (int c = 0; c < NCH; ++c) fb[c] = 0.f;
            #pragma unroll
            for (int c = 0; c <= 40; ++c) {
                #pragma unroll
                for (int b = T.start[c]; b < T.start[c + 1]; ++b) {
                    float xv = fr[b];
                    const float wa = T.w[b];
                    if (c < 40) fb[c]     = fmaf(wa, xv, fb[c]);
                    if (c >= 1) fb[c - 1] = fmaf(1.0f - wa, xv, fb[c - 1]);
                }
            }

            // ---- equal-loudness + cube-root compression ----
            float ys[NY];
            #pragma unroll
            for (int c = 0; c < NCH; ++c) {
                float v = fmaxf(fb[c], 1e-5f) * T.eql[c];
                ys[c + 1] = __expf(0.33f * __logf(v));
            }
            ys[0] = ys[1];
            ys[NY - 1] = ys[NY - 2];

            // ---- 17x42 cosine transform, literal coefficients ----
            float r[NR];
            #pragma unroll
            for (int l = 0; l < NR; ++l) {
                float acc = 0.f;
                #pragma unroll
                for (int j = 0; j < NY; ++j) acc = fmaf(T.ct[l][j], ys[j], acc);
                r[l] = acc;
            }

            // ---- Levinson-Durbin (v_rcp instead of full-precision divide) ----
            float a[MORD];
            #pragma unroll
            for (int i = 0; i < MORD; ++i) a[i] = 0.f;
            float E = r[0];
            #pragma unroll
            for (int i = 1; i <= MORD; ++i) {
                float acc = r[i];
                #pragma unroll
                for (int j = 0; j < i - 1; ++j) acc = fmaf(a[j], r[i - 1 - j], acc);
                float k = -acc * __builtin_amdgcn_rcpf(E);
                const int half = (i - 1) / 2;
                #pragma unroll
                for (int j = 0; j < half; ++j) {
                    float t1 = a[j], t2 = a[i - 2 - j];
                    a[j]         = fmaf(k, t2, t1);
                    a[i - 2 - j] = fmaf(k, t1, t2);
                }
                if ((i - 1) & 1) a[half] = fmaf(k, a[half], a[half]);
                a[i - 1] = k;
                E = E * (1.f - k * k);
            }

            // ---- LPC -> cepstrum (c[0] unused), lifter, store ----
            float cc[NR];
            #pragma unroll
            for (int m = 1; m <= MORD; ++m) {
                float acc = a[m - 1];
                #pragma unroll
                for (int k2 = 1; k2 < m; ++k2)
                    acc = fmaf(((float)k2 / (float)m) * cc[k2], a[m - k2 - 1], acc);
                cc[m] = -acc;
            }

            float o[16];
            #pragma unroll
            for (int m = 1; m <= MORD; ++m) o[m - 1] = cc[m] * T.lift[m];

            float4* op = reinterpret_cast<float4*>(out + (size_t)frame * 16);
            op[0] = make_float4(o[0],  o[1],  o[2],  o[3]);
            op[1] = make_float4(o[4],  o[5],  o[6],  o[7]);
            op[2] = make_float4(o[8],  o[9],  o[10], o[11]);
            op[3] = make_float4(o[12], o[13], o[14], o[15]);
        }
    }
}

extern "C" void kernel_launch(void* const* d_in, const int* in_sizes, int n_in,
                              void* d_out, int out_size, void* d_ws, size_t ws_size,
                              hipStream_t stream) {
    const float* x   = (const float*)d_in[0];
    float*      outp = (float*)d_out;
    int nframes = in_sizes[0] / NBINS;                          // 131072
    int nblocks = (nframes + SLABS * FPB - 1) / (SLABS * FPB);  // 256 -> 1 block/CU
    plp_kernel<<<nblocks, FPB, 0, stream>>>(x, outp, nframes);
}

// Round 5
// 203.939 us; speedup vs baseline: 1.0466x; 1.0466x over previous
//
#include <hip/hip_runtime.h>

#define NCH    40
#define MORD   16
#define NR     17
#define NY     42
#define NBINS  257
#define FPB    64                 // frames per block/slab
#define SLABF  (FPB * NBINS)      // 16448 floats = 65792 B
#define NF4    (SLABF / 4)        // 4112 float4s per slab

// ---------------- compile-time table generation (double precision) ----------------
namespace cfg {

constexpr double PI  = 3.14159265358979323846264338327950288;
constexpr double LN2 = 0.693147180559945309417232121458176568;

constexpr double cexp(double x) {
    double t = 1.0, s = 1.0;
    for (int i = 1; i < 40; ++i) { t *= x / i; s += t; }
    return s;
}

constexpr double clog(double z) {
    double lg = 0.0;
    while (z > 1.4142135623730951) { z *= 0.5; lg += LN2; }
    while (z < 0.7071067811865476) { z *= 2.0; lg -= LN2; }
    double u = (z - 1.0) / (z + 1.0), u2 = u * u, t = u, s = u;
    for (int k = 1; k < 24; ++k) { t *= u2; s += t / (2.0 * k + 1.0); }
    return lg + 2.0 * s;
}

constexpr double ccos(double x) {
    double tp = 2.0 * PI;
    double q = x / tp;
    long long k = (long long)(q + (q >= 0.0 ? 0.5 : -0.5));
    double r = x - (double)k * tp;
    double r2 = r * r, t = 1.0, s = 1.0;
    for (int i = 1; i < 20; ++i) { t *= -r2 / ((2.0 * i - 1.0) * (2.0 * i)); s += t; }
    return s;
}

constexpr double csin(double x) { return ccos(x - PI / 2.0); }

struct Tab {
    int   start[43];
    float w[257];
    float eql[NCH];
    float lift[NR];
    float ct[NR][NY];
    constexpr Tab() : start(), w(), eql(), lift(), ct() {
        const double lmax  = clog(87.0 / 7.0);
        const double U1127 = lmax / 41.0;
        for (int c = 0; c <= 41; ++c) {
            double thr = 22.4 * (cexp((double)c * U1127) - 1.0);
            int s = (int)thr + 1;
            if (s < 1) s = 1;
            if (s > 256) s = 256;
            start[c] = s;
        }
        start[42 - 1] = start[41];
        for (int c = 0; c <= 40; ++c) {
            for (int b = start[c]; b < start[c + 1]; ++b) {
                double mel = 1127.0 * clog(1.0 + (double)b * 31.25 / 700.0);
                double t   = mel / (1127.0 * U1127);
                w[b] = (float)(t - (double)c);
            }
        }
        for (int c = 0; c < NCH; ++c) {
            double cf = 700.0 * (cexp((double)(c + 1) * U1127) - 1.0);
            double f2 = cf * cf;
            double e  = f2 / (f2 + 160000.0);
            e = e * e * (f2 + 1440000.0) / (f2 + 9610000.0);
            eql[c] = (float)e;
        }
        for (int m = 0; m < NR; ++m)
            lift[m] = (float)(1.0 + 11.0 * csin(PI * (double)m / 22.0));
        lift[0] = 2.0f;
        for (int l = 0; l < NR; ++l)
            for (int j = 0; j < NY; ++j) {
                double s = (j == 0 || j == NY - 1) ? 1.0 : 2.0;
                ct[l][j] = (float)(s * ccos(PI * (double)(j * l) / 41.0) / 82.0);
            }
    }
};

constexpr Tab T{};

} // namespace cfg

// ---- 256-thread block: 4 waves stage one 64-frame slab via VGPR float4 loads
// ---- + ds_write_b128; wave 0 computes thread-per-frame; waves 1-3 retire. ----
__global__ __launch_bounds__(256) void plp_kernel(const float* __restrict__ x,
                                                  float* __restrict__ out,
                                                  int nframes)
{
    using cfg::T;
    __shared__ float slab[SLABF];               // 65792 B -> 2 blocks/CU
    const int tid = threadIdx.x;
    const long long F0 = (long long)blockIdx.x * FPB;

    // ---- staging: coalesced float4 stream, exact linear copy (stride 257 kept) ----
    {
        const float4* gsrc = reinterpret_cast<const float4*>(x + F0 * NBINS); // 16B-aligned
        float4* lsdst = reinterpret_cast<float4*>(slab);
        const long long maxf4 = ((long long)nframes * NBINS) / 4 - F0 * NBINS / 4;
        #pragma unroll
        for (int r = 0; r < 16; ++r) {
            int i = r * 256 + tid;
            long long ii = (i < maxf4) ? i : (maxf4 - 1);   // clamp (never hit at 131072 frames)
            lsdst[i] = gsrc[ii];
        }
        if (tid < NF4 - 4096) {                 // tail: 16 float4s
            int i = 4096 + tid;
            long long ii = (i < maxf4) ? i : (maxf4 - 1);
            lsdst[i] = gsrc[ii];
        }
    }
    __syncthreads();

    if (tid >= FPB) return;                     // waves 1-3 retire, free issue slots

    const long long frame = F0 + tid;
    if (frame >= nframes) return;
    const float* fr = slab + tid * NBINS;       // bank (tid+b)%32 -> 2-way, free

    // ---- sparse mel filterbank: compile-time indices & literal weights ----
    float fb[NCH];
    #pragma unroll
    for (int c = 0; c < NCH; ++c) fb[c] = 0.f;
    #pragma unroll
    for (int c = 0; c <= 40; ++c) {
        #pragma unroll
        for (int b = T.start[c]; b < T.start[c + 1]; ++b) {
            float xv = fr[b];
            const float wa = T.w[b];
            if (c < 40) fb[c]     = fmaf(wa, xv, fb[c]);
            if (c >= 1) fb[c - 1] = fmaf(1.0f - wa, xv, fb[c - 1]);
        }
    }

    // ---- equal-loudness + cube-root compression ----
    float ys[NY];
    #pragma unroll
    for (int c = 0; c < NCH; ++c) {
        float v = fmaxf(fb[c], 1e-5f) * T.eql[c];
        ys[c + 1] = __expf(0.33f * __logf(v));
    }
    ys[0] = ys[1];
    ys[NY - 1] = ys[NY - 2];

    // ---- 17x42 cosine transform, literal coefficients ----
    float r[NR];
    #pragma unroll
    for (int l = 0; l < NR; ++l) {
        float acc = 0.f;
        #pragma unroll
        for (int j = 0; j < NY; ++j) acc = fmaf(T.ct[l][j], ys[j], acc);
        r[l] = acc;
    }

    // ---- Levinson-Durbin (v_rcp) ----
    float a[MORD];
    #pragma unroll
    for (int i = 0; i < MORD; ++i) a[i] = 0.f;
    float E = r[0];
    #pragma unroll
    for (int i = 1; i <= MORD; ++i) {
        float acc = r[i];
        #pragma unroll
        for (int j = 0; j < i - 1; ++j) acc = fmaf(a[j], r[i - 1 - j], acc);
        float k = -acc * __builtin_amdgcn_rcpf(E);
        const int half = (i - 1) / 2;
        #pragma unroll
        for (int j = 0; j < half; ++j) {
            float t1 = a[j], t2 = a[i - 2 - j];
            a[j]         = fmaf(k, t2, t1);
            a[i - 2 - j] = fmaf(k, t1, t2);
        }
        if ((i - 1) & 1) a[half] = fmaf(k, a[half], a[half]);
        a[i - 1] = k;
        E = E * (1.f - k * k);
    }

    // ---- LPC -> cepstrum (c[0] unused), lifter, store ----
    float cc[NR];
    #pragma unroll
    for (int m = 1; m <= MORD; ++m) {
        float acc = a[m - 1];
        #pragma unroll
        for (int k2 = 1; k2 < m; ++k2)
            acc = fmaf(((float)k2 / (float)m) * cc[k2], a[m - k2 - 1], acc);
        cc[m] = -acc;
    }

    float o[16];
    #pragma unroll
    for (int m = 1; m <= MORD; ++m) o[m - 1] = cc[m] * T.lift[m];

    float4* op = reinterpret_cast<float4*>(out + (size_t)frame * 16);
    op[0] = make_float4(o[0],  o[1],  o[2],  o[3]);
    op[1] = make_float4(o[4],  o[5],  o[6],  o[7]);
    op[2] = make_float4(o[8],  o[9],  o[10], o[11]);
    op[3] = make_float4(o[12], o[13], o[14], o[15]);
}

extern "C" void kernel_launch(void* const* d_in, const int* in_sizes, int n_in,
                              void* d_out, int out_size, void* d_ws, size_t ws_size,
                              hipStream_t stream) {
    const float* x   = (const float*)d_in[0];
    float*      outp = (float*)d_out;
    int nframes = in_sizes[0] / NBINS;                 // 131072
    int nblocks = (nframes + FPB - 1) / FPB;           // 2048
    plp_kernel<<<nblocks, 256, 0, stream>>>(x, outp, nframes);
}